// Round 2
// 754.421 us; speedup vs baseline: 1.0162x; 1.0162x over previous
//
#include <hip/hip_runtime.h>
#include <hip/hip_bf16.h>
#include <hip/hip_fp8.h>

#define N_NODES 100000
#define N_EDGES 3200000
#define D_IN 512
#define D_HID 256
#define D_OUT 64
#define M_PAD 100096  // 782 * 128

#define NB 782    // row buckets of 128 rows (row >> 7)
#define EPB 8192  // edges per binning block
#define NBLK_BIN ((N_EDGES + EPB - 1) / EPB)  // 391

typedef __attribute__((ext_vector_type(8))) short bf16x8;
typedef __attribute__((ext_vector_type(4))) float f32x4;

__device__ __forceinline__ unsigned short f2bf(float f) {
    __hip_bfloat16 h = __float2bfloat16(f);
    return *reinterpret_cast<unsigned short*>(&h);
}
__device__ __forceinline__ float f8f(unsigned int byte) {  // fp8 e4m3 -> f32 (HW cvt on gfx950)
    __hip_fp8_e4m3 t;
    t.__x = (__hip_fp8_storage_t)byte;
    return (float)t;
}

// async global->LDS, 16B per lane. Dest must be linear (base + lane*16).
__device__ __forceinline__ void gload_lds16(const void* g, void* l) {
    __builtin_amdgcn_global_load_lds(
        (const __attribute__((address_space(1))) unsigned int*)g,
        (__attribute__((address_space(3))) unsigned int*)l, 16, 0, 0);
}

// ---------------- small casts ----------------

__global__ void cast_w1t_kernel(const float* __restrict__ w1, __hip_bfloat16* __restrict__ w1t) {
    int i = blockIdx.x * 256 + threadIdx.x;
    if (i >= D_IN * D_HID) return;
    int k = i / D_HID, n = i % D_HID;
    w1t[n * D_IN + k] = __float2bfloat16(w1[i]);
}

__global__ void cast_w2t_kernel(const float* __restrict__ w2, __hip_bfloat16* __restrict__ w2t) {
    int i = blockIdx.x * 256 + threadIdx.x;
    if (i >= D_HID * D_OUT) return;
    int k = i / D_OUT, n = i % D_OUT;
    w2t[n * D_HID + k] = __float2bfloat16(w2[i]);
}

// ---------------- CSR build (two-phase binned) ----------------

__global__ __launch_bounds__(256) void hist_bucket_kernel(const int* __restrict__ row,
                                                          int* __restrict__ gcnt) {
    __shared__ int cnt[NB];
    for (int i = threadIdx.x; i < NB; i += 256) cnt[i] = 0;
    __syncthreads();
    int base = blockIdx.x * EPB;
    for (int i = threadIdx.x; i < EPB; i += 256) {
        int e = base + i;
        if (e < N_EDGES) atomicAdd(&cnt[row[e] >> 7], 1);
    }
    __syncthreads();
    for (int i = threadIdx.x; i < NB; i += 256) {
        int c = cnt[i];
        if (c) atomicAdd(&gcnt[i], c);
    }
}

__global__ void scan_nb_kernel(const int* __restrict__ gcnt, int* __restrict__ boff,
                               int* __restrict__ gcur, int* __restrict__ offsets) {
    __shared__ int smem[1024];
    int t = threadIdx.x;
    int v = (t < NB) ? gcnt[t] : 0;
    smem[t] = v;
    __syncthreads();
    for (int off = 1; off < 1024; off <<= 1) {
        int u = (t >= off) ? smem[t - off] : 0;
        __syncthreads();
        smem[t] += u;
        __syncthreads();
    }
    int excl = smem[t] - v;
    if (t < NB) { boff[t] = excl; gcur[t] = excl; }
    if (t == 1023) boff[NB] = smem[1023];
    if (t == 0) offsets[N_NODES] = N_EDGES;
}

__global__ __launch_bounds__(256) void bin_kernel(const int* __restrict__ row,
                                                  const int* __restrict__ col,
                                                  const float* __restrict__ ew,
                                                  int* __restrict__ gcur,
                                                  int2* __restrict__ bucketed) {
    __shared__ int cnt[NB];
    __shared__ int cur[NB];
    for (int i = threadIdx.x; i < NB; i += 256) cnt[i] = 0;
    __syncthreads();
    int base = blockIdx.x * EPB;
    for (int i = threadIdx.x; i < EPB; i += 256) {
        int e = base + i;
        if (e < N_EDGES) atomicAdd(&cnt[row[e] >> 7], 1);
    }
    __syncthreads();
    for (int i = threadIdx.x; i < NB; i += 256) {
        int c = cnt[i];
        cur[i] = c ? atomicAdd(&gcur[i], c) : 0;
    }
    __syncthreads();
    for (int i = threadIdx.x; i < EPB; i += 256) {
        int e = base + i;
        if (e < N_EDGES) {
            int r = row[e];
            int b = r >> 7;
            int pos = atomicAdd(&cur[b], 1);
            bucketed[pos] = make_int2((col[e] << 7) | (r & 127), __float_as_int(ew[e]));
        }
    }
}

__global__ __launch_bounds__(256) void csr_kernel(const int2* __restrict__ bucketed,
                                                  const int* __restrict__ boff,
                                                  int* __restrict__ offsets,
                                                  int2* __restrict__ edges) {
    __shared__ int rcnt[128];
    __shared__ int sc[128];
    __shared__ int rcur[128];
    int b = blockIdx.x;
    int t = threadIdx.x;
    int s = boff[b], e2 = boff[b + 1];
    if (t < 128) rcnt[t] = 0;
    __syncthreads();
    for (int i = s + t; i < e2; i += 256) atomicAdd(&rcnt[bucketed[i].x & 127], 1);
    __syncthreads();
    if (t < 128) sc[t] = rcnt[t];
    __syncthreads();
    for (int off = 1; off < 128; off <<= 1) {
        int u = 0;
        if (t < 128 && t >= off) u = sc[t - off];
        __syncthreads();
        if (t < 128) sc[t] += u;
        __syncthreads();
    }
    if (t < 128) {
        int excl = sc[t] - rcnt[t];
        rcur[t] = excl;
        int rglob = b * 128 + t;
        if (rglob < N_NODES) offsets[rglob] = s + excl;
    }
    __syncthreads();
    for (int i = s + t; i < e2; i += 256) {
        int2 p = bucketed[i];
        int r = p.x & 127;
        int pos = atomicAdd(&rcur[r], 1);
        edges[s + pos] = make_int2(p.x >> 7, p.y);
    }
}

// ---------------- MFMA GEMM (m97 structure: global_load_lds + XOR swizzle) ----------------
// C[M x N] = A[M x K] * Bt[N x K]^T. A either fp32 (converted at LDS->frag read) or bf16.
// LDS is LINEAR (global_load_lds requirement); bank-conflict swizzle is applied by
// pre-swizzling the GLOBAL source address (m173 pattern) and un-swizzling on ds_read.
// OUT_MODE: 0 = fp32, 1 = bf16, 2 = fp8 e4m3.

template <int BN, int WROWS, int WCOLS, int MT, int NT, bool A_F32, int OUT_MODE>
__global__ __launch_bounds__(256) void gemm_bf16_kernel(
    const void* __restrict__ Av, const __hip_bfloat16* __restrict__ Bt,
    void* __restrict__ Cv, int K, int Mvalid, int Mload, int Nld) {
    constexpr int BM = 128;
    constexpr int BK = 32;
    constexpr int ABYTES = BM * BK * (A_F32 ? 4 : 2);
    constexpr int BBYTES = BN * BK * 2;
    __shared__ __align__(16) unsigned char As[ABYTES];
    __shared__ __align__(16) unsigned char Bs[BBYTES];

    const int tid = threadIdx.x;
    const int m0 = blockIdx.x * BM;
    const int n0 = blockIdx.y * BN;
    const int w = tid >> 6, lane = tid & 63;
    const int wr = w % WROWS, wc = w / WROWS;
    const int mbase = wr * MT * 16, nbase = wc * NT * 16;
    const int quad = lane >> 4, l16 = lane & 15;

    f32x4 acc[MT][NT] = {};

    constexpr int AISS = ABYTES / (256 * 16);
    constexpr int BISS = BBYTES / (256 * 16);

    for (int k0 = 0; k0 < K; k0 += BK) {
        // ---- stage A via global_load_lds (linear dest, pre-swizzled source) ----
#pragma unroll
        for (int c = 0; c < AISS; ++c) {
            int idx = c * 256 + tid;
            if constexpr (A_F32) {
                int r = idx >> 3, slot = idx & 7;  // fp32 row = 128B = 8 x 16B slots
                if (m0 + r < Mload) {
                    const float* src = (const float*)Av + (size_t)(m0 + r) * K + k0 +
                                       ((slot ^ (r & 7)) << 2);
                    gload_lds16(src, As + idx * 16);
                }
            } else {
                int r = idx >> 2, slot = idx & 3;  // bf16 row = 64B = 4 x 16B slots
                if (m0 + r < Mload) {
                    const __hip_bfloat16* src = (const __hip_bfloat16*)Av +
                                                (size_t)(m0 + r) * K + k0 +
                                                ((slot ^ (r & 3)) << 3);
                    gload_lds16(src, As + idx * 16);
                }
            }
        }
        // ---- stage B ----
#pragma unroll
        for (int c = 0; c < BISS; ++c) {
            int idx = c * 256 + tid;
            int r = idx >> 2, slot = idx & 3;
            const __hip_bfloat16* src = Bt + (size_t)(n0 + r) * K + k0 +
                                        ((slot ^ (r & 3)) << 3);
            gload_lds16(src, Bs + idx * 16);
        }
        __syncthreads();  // compiler emits vmcnt(0) drain before s_barrier

        bf16x8 af[MT], bfr[NT];
#pragma unroll
        for (int mt = 0; mt < MT; ++mt) {
            int r = mbase + mt * 16 + l16;
            if constexpr (A_F32) {
                const float4* rowp = (const float4*)(As + r * 128);
                int sw = r & 7;
                float4 f0 = rowp[(quad * 2) ^ sw];
                float4 f1 = rowp[(quad * 2 + 1) ^ sw];
                union { bf16x8 v; unsigned short u[8]; } o;
                o.u[0] = f2bf(f0.x); o.u[1] = f2bf(f0.y);
                o.u[2] = f2bf(f0.z); o.u[3] = f2bf(f0.w);
                o.u[4] = f2bf(f1.x); o.u[5] = f2bf(f1.y);
                o.u[6] = f2bf(f1.z); o.u[7] = f2bf(f1.w);
                af[mt] = o.v;
            } else {
                af[mt] = *(const bf16x8*)(As + r * 64 + ((quad ^ (r & 3)) * 16));
            }
        }
#pragma unroll
        for (int nt = 0; nt < NT; ++nt) {
            int r = nbase + nt * 16 + l16;
            bfr[nt] = *(const bf16x8*)(Bs + r * 64 + ((quad ^ (r & 3)) * 16));
        }
#pragma unroll
        for (int mt = 0; mt < MT; ++mt)
#pragma unroll
            for (int nt = 0; nt < NT; ++nt)
                acc[mt][nt] = __builtin_amdgcn_mfma_f32_16x16x32_bf16(af[mt], bfr[nt],
                                                                      acc[mt][nt], 0, 0, 0);
        __syncthreads();
    }

#pragma unroll
    for (int mt = 0; mt < MT; ++mt)
#pragma unroll
        for (int nt = 0; nt < NT; ++nt)
#pragma unroll
            for (int r = 0; r < 4; ++r) {
                int rowi = m0 + mbase + mt * 16 + quad * 4 + r;
                int coli = n0 + nbase + nt * 16 + l16;
                if (rowi < Mvalid) {
                    if constexpr (OUT_MODE == 0) {
                        ((float*)Cv)[(size_t)rowi * Nld + coli] = acc[mt][nt][r];
                    } else if constexpr (OUT_MODE == 1) {
                        ((__hip_bfloat16*)Cv)[(size_t)rowi * Nld + coli] =
                            __float2bfloat16(acc[mt][nt][r]);
                    } else {
                        __hip_fp8_e4m3 q(acc[mt][nt][r]);
                        ((unsigned char*)Cv)[(size_t)rowi * Nld + coli] = q.__x;
                    }
                }
            }
}

// ---------------- aggregation ----------------

// layer 1: hb = relu(agg(sup1 fp8) + b1) -> bf16; zero-fills pad rows. One wave per node.
// Lane handles 4 fp8 (one uint) at cols [4*lane, 4*lane+4).
__global__ __launch_bounds__(256) void agg1_kernel(
    const unsigned int* __restrict__ sup,  // fp8 [N_NODES][256] as uint[N_NODES][64]
    const int* __restrict__ offsets, const int2* __restrict__ edges,
    const float* __restrict__ b1, __hip_bfloat16* __restrict__ hb) {
    int n = blockIdx.x * 4 + (threadIdx.x >> 6);
    int lane = threadIdx.x & 63;
    if (n >= M_PAD) return;
    if (n >= N_NODES) {
        *reinterpret_cast<ushort4*>(&hb[(size_t)n * D_HID + lane * 4]) = ushort4{0, 0, 0, 0};
        return;
    }
    int s = offsets[n], e2 = offsets[n + 1];
    float a0 = 0.f, a1 = 0.f, a2 = 0.f, a3 = 0.f;
    int e = s;
    for (; e + 8 <= e2; e += 8) {
        int2 m[8];
        unsigned int v[8];
#pragma unroll
        for (int i = 0; i < 8; ++i) m[i] = edges[e + i];
#pragma unroll
        for (int i = 0; i < 8; ++i) v[i] = sup[(size_t)m[i].x * 64 + lane];
#pragma unroll
        for (int i = 0; i < 8; ++i) {
            float wv = __int_as_float(m[i].y);
            a0 += wv * f8f(v[i] & 0xff);
            a1 += wv * f8f((v[i] >> 8) & 0xff);
            a2 += wv * f8f((v[i] >> 16) & 0xff);
            a3 += wv * f8f(v[i] >> 24);
        }
    }
    for (; e < e2; ++e) {
        int2 m = edges[e];
        unsigned int v = sup[(size_t)m.x * 64 + lane];
        float wv = __int_as_float(m.y);
        a0 += wv * f8f(v & 0xff);
        a1 += wv * f8f((v >> 8) & 0xff);
        a2 += wv * f8f((v >> 16) & 0xff);
        a3 += wv * f8f(v >> 24);
    }
    float4 bb = reinterpret_cast<const float4*>(b1)[lane];
    ushort4 o;
    o.x = f2bf(fmaxf(a0 + bb.x, 0.f));
    o.y = f2bf(fmaxf(a1 + bb.y, 0.f));
    o.z = f2bf(fmaxf(a2 + bb.z, 0.f));
    o.w = f2bf(fmaxf(a3 + bb.w, 0.f));
    *reinterpret_cast<ushort4*>(&hb[(size_t)n * D_HID + lane * 4]) = o;
}

// layer 2: agg(sup2 bf16) + b2, log_softmax over 64 dims. One wave per node.
__global__ __launch_bounds__(256) void agg2_softmax_kernel(
    const unsigned short* __restrict__ sup2, const int* __restrict__ offsets,
    const int2* __restrict__ edges, const float* __restrict__ b2, float* __restrict__ out) {
    int n = blockIdx.x * 4 + (threadIdx.x >> 6);
    int j = threadIdx.x & 63;
    if (n >= N_NODES) return;
    int s = offsets[n], e2 = offsets[n + 1];
    float acc = 0.f;
    int e = s;
    for (; e + 4 <= e2; e += 4) {
        int2 m0 = edges[e], m1 = edges[e + 1], m2 = edges[e + 2], m3 = edges[e + 3];
        float v0 = __uint_as_float((unsigned)sup2[(size_t)m0.x * D_OUT + j] << 16);
        float v1 = __uint_as_float((unsigned)sup2[(size_t)m1.x * D_OUT + j] << 16);
        float v2 = __uint_as_float((unsigned)sup2[(size_t)m2.x * D_OUT + j] << 16);
        float v3 = __uint_as_float((unsigned)sup2[(size_t)m3.x * D_OUT + j] << 16);
        acc += __int_as_float(m0.y) * v0;
        acc += __int_as_float(m1.y) * v1;
        acc += __int_as_float(m2.y) * v2;
        acc += __int_as_float(m3.y) * v3;
    }
    for (; e < e2; ++e) {
        int2 m = edges[e];
        acc += __int_as_float(m.y) * __uint_as_float((unsigned)sup2[(size_t)m.x * D_OUT + j] << 16);
    }
    acc += b2[j];
    float m = acc;
#pragma unroll
    for (int o = 32; o > 0; o >>= 1) m = fmaxf(m, __shfl_xor(m, o, 64));
    float ex = __expf(acc - m);
    float ssum = ex;
#pragma unroll
    for (int o = 32; o > 0; o >>= 1) ssum += __shfl_xor(ssum, o, 64);
    out[(size_t)n * D_OUT + j] = acc - m - __logf(ssum);
}

// ---------------- launch ----------------

extern "C" void kernel_launch(void* const* d_in, const int* in_sizes, int n_in,
                              void* d_out, int out_size, void* d_ws, size_t ws_size,
                              hipStream_t stream) {
    const float* x  = (const float*)d_in[0];
    const int* row  = (const int*)d_in[1];
    const int* col  = (const int*)d_in[2];
    const float* ew = (const float*)d_in[3];
    const float* w1 = (const float*)d_in[4];
    const float* b1 = (const float*)d_in[5];
    const float* w2 = (const float*)d_in[6];
    const float* b2 = (const float*)d_in[7];
    float* out = (float*)d_out;

    char* ws = (char*)d_ws;
    size_t off = 0;
    auto alloc = [&](size_t bytes) -> void* {
        void* p = ws + off;
        off = (off + bytes + 255) & ~(size_t)255;
        return p;
    };

    __hip_bfloat16* w1t  = (__hip_bfloat16*)alloc((size_t)D_HID * D_IN * 2);
    __hip_bfloat16* w2t  = (__hip_bfloat16*)alloc((size_t)D_OUT * D_HID * 2);
    unsigned char* sup1  = (unsigned char*)alloc((size_t)N_NODES * D_HID);      // fp8, 25.6 MB
    __hip_bfloat16* hb   = (__hip_bfloat16*)alloc((size_t)M_PAD * D_HID * 2);   // 51.2 MB
    unsigned short* sup2 = (unsigned short*)alloc((size_t)N_NODES * D_OUT * 2); // bf16, 12.8 MB
    int* offsets         = (int*)alloc((size_t)(N_NODES + 1) * 4);
    int* gcnt            = (int*)alloc((size_t)NB * 4);
    int* boff            = (int*)alloc((size_t)(NB + 1) * 4);
    int* gcur            = (int*)alloc((size_t)NB * 4);
    int2* edges          = (int2*)alloc((size_t)N_EDGES * 8);                   // 25.6 MB
    int2* bucketed       = (int2*)alloc((size_t)N_EDGES * 8);                   // 25.6 MB

    // ---- CSR build ----
    hipMemsetAsync(gcnt, 0, (size_t)NB * 4, stream);
    hist_bucket_kernel<<<NBLK_BIN, 256, 0, stream>>>(row, gcnt);
    scan_nb_kernel<<<1, 1024, 0, stream>>>(gcnt, boff, gcur, offsets);
    bin_kernel<<<NBLK_BIN, 256, 0, stream>>>(row, col, ew, gcur, bucketed);
    csr_kernel<<<NB, 256, 0, stream>>>(bucketed, boff, offsets, edges);

    // ---- weight casts ----
    cast_w1t_kernel<<<(D_IN * D_HID + 255) / 256, 256, 0, stream>>>(w1, w1t);
    cast_w2t_kernel<<<(D_HID * D_OUT + 255) / 256, 256, 0, stream>>>(w2, w2t);

    // ---- layer 1: sup1(fp8) = bf16(x) @ w1t^T ; hb = relu(agg + b1) ----
    gemm_bf16_kernel<128, 2, 2, 4, 4, true, 2><<<dim3(M_PAD / 128, D_HID / 128), 256, 0, stream>>>(
        x, w1t, sup1, D_IN, N_NODES, N_NODES, D_HID);
    agg1_kernel<<<M_PAD / 4, 256, 0, stream>>>((const unsigned int*)sup1, offsets, edges, b1, hb);

    // ---- layer 2: sup2(bf16) = hb @ w2t^T ; out = log_softmax(agg + b2) ----
    gemm_bf16_kernel<64, 4, 1, 2, 4, false, 1><<<dim3(M_PAD / 128, 1), 256, 0, stream>>>(
        hb, w2t, sup2, D_HID, N_NODES, M_PAD, D_OUT);
    agg2_softmax_kernel<<<(N_NODES + 3) / 4, 256, 0, stream>>>(sup2, offsets, edges, b2, out);
}

// Round 4
// 727.916 us; speedup vs baseline: 1.0533x; 1.0364x over previous
//
#include <hip/hip_runtime.h>
#include <hip/hip_bf16.h>
#include <hip/hip_fp8.h>

#define N_NODES 100000
#define N_EDGES 3200000
#define D_IN 512
#define D_HID 256
#define D_OUT 64
#define M_PAD 100096  // 782 * 128

#define NB 782    // row buckets of 128 rows (row >> 7)
#define EPB 8192  // edges per binning block
#define NBLK_BIN ((N_EDGES + EPB - 1) / EPB)  // 391

typedef __attribute__((ext_vector_type(8))) short bf16x8;
typedef __attribute__((ext_vector_type(4))) float f32x4;
typedef __attribute__((ext_vector_type(2))) float f32x2;

__device__ __forceinline__ unsigned short f2bf(float f) {
    __hip_bfloat16 h = __float2bfloat16(f);
    return *reinterpret_cast<unsigned short*>(&h);
}
__device__ __forceinline__ float f8f(unsigned int byte) {  // fp8 e4m3 -> f32 (HW cvt on gfx950)
    __hip_fp8_e4m3 t;
    t.__x = (__hip_fp8_storage_t)byte;
    return (float)t;
}

// 8 x fp8 (uint2) -> 8 f32 multiply-accumulate with packed HW converts.
__device__ __forceinline__ void acc8_fp8(float* a, float wv, uint2 v) {
#if __has_builtin(__builtin_amdgcn_cvt_pk_f32_fp8)
    f32x2 p0 = __builtin_amdgcn_cvt_pk_f32_fp8(v.x, false);
    f32x2 p1 = __builtin_amdgcn_cvt_pk_f32_fp8(v.x, true);
    f32x2 p2 = __builtin_amdgcn_cvt_pk_f32_fp8(v.y, false);
    f32x2 p3 = __builtin_amdgcn_cvt_pk_f32_fp8(v.y, true);
    a[0] += wv * p0.x; a[1] += wv * p0.y;
    a[2] += wv * p1.x; a[3] += wv * p1.y;
    a[4] += wv * p2.x; a[5] += wv * p2.y;
    a[6] += wv * p3.x; a[7] += wv * p3.y;
#else
    a[0] += wv * f8f(v.x & 0xff);
    a[1] += wv * f8f((v.x >> 8) & 0xff);
    a[2] += wv * f8f((v.x >> 16) & 0xff);
    a[3] += wv * f8f(v.x >> 24);
    a[4] += wv * f8f(v.y & 0xff);
    a[5] += wv * f8f((v.y >> 8) & 0xff);
    a[6] += wv * f8f((v.y >> 16) & 0xff);
    a[7] += wv * f8f(v.y >> 24);
#endif
}

// async global->LDS, 16B per lane. Dest must be linear (base + lane*16).
__device__ __forceinline__ void gload_lds16(const void* g, void* l) {
    __builtin_amdgcn_global_load_lds(
        (const __attribute__((address_space(1))) unsigned int*)g,
        (__attribute__((address_space(3))) unsigned int*)l, 16, 0, 0);
}

// ---------------- small casts ----------------

__global__ void cast_w1t_kernel(const float* __restrict__ w1, __hip_bfloat16* __restrict__ w1t) {
    int i = blockIdx.x * 256 + threadIdx.x;
    if (i >= D_IN * D_HID) return;
    int k = i / D_HID, n = i % D_HID;
    w1t[n * D_IN + k] = __float2bfloat16(w1[i]);
}

__global__ void cast_w2t_kernel(const float* __restrict__ w2, __hip_bfloat16* __restrict__ w2t) {
    int i = blockIdx.x * 256 + threadIdx.x;
    if (i >= D_HID * D_OUT) return;
    int k = i / D_OUT, n = i % D_OUT;
    w2t[n * D_HID + k] = __float2bfloat16(w2[i]);
}

// ---------------- CSR build (two-phase binned) ----------------

__global__ __launch_bounds__(256) void hist_bucket_kernel(const int* __restrict__ row,
                                                          int* __restrict__ gcnt) {
    __shared__ int cnt[NB];
    for (int i = threadIdx.x; i < NB; i += 256) cnt[i] = 0;
    __syncthreads();
    int base = blockIdx.x * EPB;
    for (int i = threadIdx.x; i < EPB; i += 256) {
        int e = base + i;
        if (e < N_EDGES) atomicAdd(&cnt[row[e] >> 7], 1);
    }
    __syncthreads();
    for (int i = threadIdx.x; i < NB; i += 256) {
        int c = cnt[i];
        if (c) atomicAdd(&gcnt[i], c);
    }
}

__global__ void scan_nb_kernel(const int* __restrict__ gcnt, int* __restrict__ boff,
                               int* __restrict__ gcur, int* __restrict__ offsets) {
    __shared__ int smem[1024];
    int t = threadIdx.x;
    int v = (t < NB) ? gcnt[t] : 0;
    smem[t] = v;
    __syncthreads();
    for (int off = 1; off < 1024; off <<= 1) {
        int u = (t >= off) ? smem[t - off] : 0;
        __syncthreads();
        smem[t] += u;
        __syncthreads();
    }
    int excl = smem[t] - v;
    if (t < NB) { boff[t] = excl; gcur[t] = excl; }
    if (t == 1023) boff[NB] = smem[1023];
    if (t == 0) offsets[N_NODES] = N_EDGES;
}

__global__ __launch_bounds__(256) void bin_kernel(const int* __restrict__ row,
                                                  const int* __restrict__ col,
                                                  const float* __restrict__ ew,
                                                  int* __restrict__ gcur,
                                                  int2* __restrict__ bucketed) {
    __shared__ int cnt[NB];
    __shared__ int cur[NB];
    for (int i = threadIdx.x; i < NB; i += 256) cnt[i] = 0;
    __syncthreads();
    int base = blockIdx.x * EPB;
    for (int i = threadIdx.x; i < EPB; i += 256) {
        int e = base + i;
        if (e < N_EDGES) atomicAdd(&cnt[row[e] >> 7], 1);
    }
    __syncthreads();
    for (int i = threadIdx.x; i < NB; i += 256) {
        int c = cnt[i];
        cur[i] = c ? atomicAdd(&gcur[i], c) : 0;
    }
    __syncthreads();
    for (int i = threadIdx.x; i < EPB; i += 256) {
        int e = base + i;
        if (e < N_EDGES) {
            int r = row[e];
            int b = r >> 7;
            int pos = atomicAdd(&cur[b], 1);
            bucketed[pos] = make_int2((col[e] << 7) | (r & 127), __float_as_int(ew[e]));
        }
    }
}

__global__ __launch_bounds__(256) void csr_kernel(const int2* __restrict__ bucketed,
                                                  const int* __restrict__ boff,
                                                  int* __restrict__ offsets,
                                                  int2* __restrict__ edges) {
    __shared__ int rcnt[128];
    __shared__ int sc[128];
    __shared__ int rcur[128];
    int b = blockIdx.x;
    int t = threadIdx.x;
    int s = boff[b], e2 = boff[b + 1];
    if (t < 128) rcnt[t] = 0;
    __syncthreads();
    for (int i = s + t; i < e2; i += 256) atomicAdd(&rcnt[bucketed[i].x & 127], 1);
    __syncthreads();
    if (t < 128) sc[t] = rcnt[t];
    __syncthreads();
    for (int off = 1; off < 128; off <<= 1) {
        int u = 0;
        if (t < 128 && t >= off) u = sc[t - off];
        __syncthreads();
        if (t < 128) sc[t] += u;
        __syncthreads();
    }
    if (t < 128) {
        int excl = sc[t] - rcnt[t];
        rcur[t] = excl;
        int rglob = b * 128 + t;
        if (rglob < N_NODES) offsets[rglob] = s + excl;
    }
    __syncthreads();
    for (int i = s + t; i < e2; i += 256) {
        int2 p = bucketed[i];
        int r = p.x & 127;
        int pos = atomicAdd(&rcur[r], 1);
        edges[s + pos] = make_int2(p.x >> 7, p.y);
    }
}

// ---------------- MFMA GEMM (m97 structure: global_load_lds + XOR swizzle) ----------------
// C[M x N] = A[M x K] * Bt[N x K]^T. A either fp32 (converted at LDS->frag read) or bf16.
// LDS is LINEAR (global_load_lds requirement); bank-conflict swizzle is applied by
// pre-swizzling the GLOBAL source address (m173 pattern) and un-swizzling on ds_read.
// OUT_MODE: 0 = fp32, 1 = bf16, 2 = fp8 e4m3.

template <int BN, int WROWS, int WCOLS, int MT, int NT, bool A_F32, int OUT_MODE>
__global__ __launch_bounds__(256) void gemm_bf16_kernel(
    const void* __restrict__ Av, const __hip_bfloat16* __restrict__ Bt,
    void* __restrict__ Cv, int K, int Mvalid, int Mload, int Nld) {
    constexpr int BM = 128;
    constexpr int BK = 32;
    constexpr int ABYTES = BM * BK * (A_F32 ? 4 : 2);
    constexpr int BBYTES = BN * BK * 2;
    __shared__ __align__(16) unsigned char As[ABYTES];
    __shared__ __align__(16) unsigned char Bs[BBYTES];

    const int tid = threadIdx.x;
    const int m0 = blockIdx.x * BM;
    const int n0 = blockIdx.y * BN;
    const int w = tid >> 6, lane = tid & 63;
    const int wr = w % WROWS, wc = w / WROWS;
    const int mbase = wr * MT * 16, nbase = wc * NT * 16;
    const int quad = lane >> 4, l16 = lane & 15;

    f32x4 acc[MT][NT] = {};

    constexpr int AISS = ABYTES / (256 * 16);
    constexpr int BISS = BBYTES / (256 * 16);

    for (int k0 = 0; k0 < K; k0 += BK) {
        // ---- stage A via global_load_lds (linear dest, pre-swizzled source) ----
#pragma unroll
        for (int c = 0; c < AISS; ++c) {
            int idx = c * 256 + tid;
            if constexpr (A_F32) {
                int r = idx >> 3, slot = idx & 7;  // fp32 row = 128B = 8 x 16B slots
                if (m0 + r < Mload) {
                    const float* src = (const float*)Av + (size_t)(m0 + r) * K + k0 +
                                       ((slot ^ (r & 7)) << 2);
                    gload_lds16(src, As + idx * 16);
                }
            } else {
                int r = idx >> 2, slot = idx & 3;  // bf16 row = 64B = 4 x 16B slots
                if (m0 + r < Mload) {
                    const __hip_bfloat16* src = (const __hip_bfloat16*)Av +
                                                (size_t)(m0 + r) * K + k0 +
                                                ((slot ^ (r & 3)) << 3);
                    gload_lds16(src, As + idx * 16);
                }
            }
        }
        // ---- stage B ----
#pragma unroll
        for (int c = 0; c < BISS; ++c) {
            int idx = c * 256 + tid;
            int r = idx >> 2, slot = idx & 3;
            const __hip_bfloat16* src = Bt + (size_t)(n0 + r) * K + k0 +
                                        ((slot ^ (r & 3)) << 3);
            gload_lds16(src, Bs + idx * 16);
        }
        __syncthreads();  // compiler emits vmcnt(0) drain before s_barrier

        bf16x8 af[MT], bfr[NT];
#pragma unroll
        for (int mt = 0; mt < MT; ++mt) {
            int r = mbase + mt * 16 + l16;
            if constexpr (A_F32) {
                const float4* rowp = (const float4*)(As + r * 128);
                int sw = r & 7;
                float4 f0 = rowp[(quad * 2) ^ sw];
                float4 f1 = rowp[(quad * 2 + 1) ^ sw];
                union { bf16x8 v; unsigned short u[8]; } o;
                o.u[0] = f2bf(f0.x); o.u[1] = f2bf(f0.y);
                o.u[2] = f2bf(f0.z); o.u[3] = f2bf(f0.w);
                o.u[4] = f2bf(f1.x); o.u[5] = f2bf(f1.y);
                o.u[6] = f2bf(f1.z); o.u[7] = f2bf(f1.w);
                af[mt] = o.v;
            } else {
                af[mt] = *(const bf16x8*)(As + r * 64 + ((quad ^ (r & 3)) * 16));
            }
        }
#pragma unroll
        for (int nt = 0; nt < NT; ++nt) {
            int r = nbase + nt * 16 + l16;
            bfr[nt] = *(const bf16x8*)(Bs + r * 64 + ((quad ^ (r & 3)) * 16));
        }
#pragma unroll
        for (int mt = 0; mt < MT; ++mt)
#pragma unroll
            for (int nt = 0; nt < NT; ++nt)
                acc[mt][nt] = __builtin_amdgcn_mfma_f32_16x16x32_bf16(af[mt], bfr[nt],
                                                                      acc[mt][nt], 0, 0, 0);
        __syncthreads();
    }

#pragma unroll
    for (int mt = 0; mt < MT; ++mt)
#pragma unroll
        for (int nt = 0; nt < NT; ++nt)
#pragma unroll
            for (int r = 0; r < 4; ++r) {
                int rowi = m0 + mbase + mt * 16 + quad * 4 + r;
                int coli = n0 + nbase + nt * 16 + l16;
                if (rowi < Mvalid) {
                    if constexpr (OUT_MODE == 0) {
                        ((float*)Cv)[(size_t)rowi * Nld + coli] = acc[mt][nt][r];
                    } else if constexpr (OUT_MODE == 1) {
                        ((__hip_bfloat16*)Cv)[(size_t)rowi * Nld + coli] =
                            __float2bfloat16(acc[mt][nt][r]);
                    } else {
                        __hip_fp8_e4m3 q(acc[mt][nt][r]);
                        ((unsigned char*)Cv)[(size_t)rowi * Nld + coli] = q.__x;
                    }
                }
            }
}

// ---------------- aggregation ----------------

// layer 1: hb = relu(agg(sup1 fp8) + b1) -> bf16; zero-fills pad rows.
// One wave per node, 2 edges per wave (one per 32-lane half); each lane owns 8 dims
// (uint2 = 8 fp8) of the gathered row; packed v_cvt_pk_f32_fp8 converts.
__global__ __launch_bounds__(256) void agg1_kernel(
    const uint2* __restrict__ sup,  // fp8 [N_NODES][256] as uint2[N_NODES][32]
    const int* __restrict__ offsets, const int2* __restrict__ edges,
    const float* __restrict__ b1, __hip_bfloat16* __restrict__ hb) {
    int n = blockIdx.x * 4 + (threadIdx.x >> 6);
    int lane = threadIdx.x & 63;
    int half = lane >> 5;
    int l32 = lane & 31;
    if (n >= M_PAD) return;
    if (n >= N_NODES) {
        if (half == 0)
            *reinterpret_cast<uint4*>(&hb[(size_t)n * D_HID + l32 * 8]) = uint4{0, 0, 0, 0};
        return;
    }
    int s = offsets[n], e2 = offsets[n + 1];
    float a[8] = {};
    int e = s + half;
    for (; e + 6 < e2; e += 8) {
        int2 m0 = edges[e], m1 = edges[e + 2], m2 = edges[e + 4], m3 = edges[e + 6];
        uint2 v0 = sup[(size_t)m0.x * 32 + l32];
        uint2 v1 = sup[(size_t)m1.x * 32 + l32];
        uint2 v2 = sup[(size_t)m2.x * 32 + l32];
        uint2 v3 = sup[(size_t)m3.x * 32 + l32];
        acc8_fp8(a, __int_as_float(m0.y), v0);
        acc8_fp8(a, __int_as_float(m1.y), v1);
        acc8_fp8(a, __int_as_float(m2.y), v2);
        acc8_fp8(a, __int_as_float(m3.y), v3);
    }
    for (; e < e2; e += 2) {
        int2 m = edges[e];
        uint2 v = sup[(size_t)m.x * 32 + l32];
        acc8_fp8(a, __int_as_float(m.y), v);
    }
    // combine the two half-wave edge partitions
#pragma unroll
    for (int i = 0; i < 8; ++i) a[i] += __shfl_xor(a[i], 32, 64);
    if (half == 0) {
        float4 bb0 = reinterpret_cast<const float4*>(b1)[l32 * 2];
        float4 bb1 = reinterpret_cast<const float4*>(b1)[l32 * 2 + 1];
        union { uint4 u4; unsigned short us[8]; } o;
        o.us[0] = f2bf(fmaxf(a[0] + bb0.x, 0.f));
        o.us[1] = f2bf(fmaxf(a[1] + bb0.y, 0.f));
        o.us[2] = f2bf(fmaxf(a[2] + bb0.z, 0.f));
        o.us[3] = f2bf(fmaxf(a[3] + bb0.w, 0.f));
        o.us[4] = f2bf(fmaxf(a[4] + bb1.x, 0.f));
        o.us[5] = f2bf(fmaxf(a[5] + bb1.y, 0.f));
        o.us[6] = f2bf(fmaxf(a[6] + bb1.z, 0.f));
        o.us[7] = f2bf(fmaxf(a[7] + bb1.w, 0.f));
        *reinterpret_cast<uint4*>(&hb[(size_t)n * D_HID + l32 * 8]) = o.u4;
    }
}

// layer 2: agg(sup2 bf16) + b2, log_softmax over 64 dims.
// One wave per node, 2 edges per wave; each lane owns 2 dims (uint = 2 bf16).
__global__ __launch_bounds__(256) void agg2_softmax_kernel(
    const unsigned int* __restrict__ sup2v,  // bf16 [N_NODES][64] as uint[N_NODES][32]
    const int* __restrict__ offsets, const int2* __restrict__ edges,
    const float* __restrict__ b2, float* __restrict__ out) {
    int n = blockIdx.x * 4 + (threadIdx.x >> 6);
    int lane = threadIdx.x & 63;
    int half = lane >> 5;
    int l32 = lane & 31;
    if (n >= N_NODES) return;
    int s = offsets[n], e2 = offsets[n + 1];
    float a0 = 0.f, a1 = 0.f;
    int e = s + half;
    for (; e + 6 < e2; e += 8) {
        int2 m0 = edges[e], m1 = edges[e + 2], m2 = edges[e + 4], m3 = edges[e + 6];
        unsigned v0 = sup2v[(size_t)m0.x * 32 + l32];
        unsigned v1 = sup2v[(size_t)m1.x * 32 + l32];
        unsigned v2 = sup2v[(size_t)m2.x * 32 + l32];
        unsigned v3 = sup2v[(size_t)m3.x * 32 + l32];
        float w0 = __int_as_float(m0.y), w1 = __int_as_float(m1.y);
        float w2 = __int_as_float(m2.y), w3 = __int_as_float(m3.y);
        a0 += w0 * __uint_as_float(v0 << 16);
        a1 += w0 * __uint_as_float(v0 & 0xffff0000u);
        a0 += w1 * __uint_as_float(v1 << 16);
        a1 += w1 * __uint_as_float(v1 & 0xffff0000u);
        a0 += w2 * __uint_as_float(v2 << 16);
        a1 += w2 * __uint_as_float(v2 & 0xffff0000u);
        a0 += w3 * __uint_as_float(v3 << 16);
        a1 += w3 * __uint_as_float(v3 & 0xffff0000u);
    }
    for (; e < e2; e += 2) {
        int2 m = edges[e];
        unsigned v = sup2v[(size_t)m.x * 32 + l32];
        float wv = __int_as_float(m.y);
        a0 += wv * __uint_as_float(v << 16);
        a1 += wv * __uint_as_float(v & 0xffff0000u);
    }
    // combine half-wave partitions (both halves end with full sums)
    a0 += __shfl_xor(a0, 32, 64);
    a1 += __shfl_xor(a1, 32, 64);
    float2 bb = reinterpret_cast<const float2*>(b2)[l32];
    a0 += bb.x;
    a1 += bb.y;
    float m = fmaxf(a0, a1);
#pragma unroll
    for (int o = 16; o > 0; o >>= 1) m = fmaxf(m, __shfl_xor(m, o, 64));
    float ssum = __expf(a0 - m) + __expf(a1 - m);
#pragma unroll
    for (int o = 16; o > 0; o >>= 1) ssum += __shfl_xor(ssum, o, 64);
    if (half == 0) {
        float lse = m + __logf(ssum);
        float2 r;
        r.x = a0 - lse;
        r.y = a1 - lse;
        reinterpret_cast<float2*>(out)[(size_t)n * 32 + l32] = r;
    }
}

// ---------------- launch ----------------

extern "C" void kernel_launch(void* const* d_in, const int* in_sizes, int n_in,
                              void* d_out, int out_size, void* d_ws, size_t ws_size,
                              hipStream_t stream) {
    const float* x  = (const float*)d_in[0];
    const int* row  = (const int*)d_in[1];
    const int* col  = (const int*)d_in[2];
    const float* ew = (const float*)d_in[3];
    const float* w1 = (const float*)d_in[4];
    const float* b1 = (const float*)d_in[5];
    const float* w2 = (const float*)d_in[6];
    const float* b2 = (const float*)d_in[7];
    float* out = (float*)d_out;

    char* ws = (char*)d_ws;
    size_t off = 0;
    auto alloc = [&](size_t bytes) -> void* {
        void* p = ws + off;
        off = (off + bytes + 255) & ~(size_t)255;
        return p;
    };

    __hip_bfloat16* w1t  = (__hip_bfloat16*)alloc((size_t)D_HID * D_IN * 2);
    __hip_bfloat16* w2t  = (__hip_bfloat16*)alloc((size_t)D_OUT * D_HID * 2);
    unsigned char* sup1  = (unsigned char*)alloc((size_t)N_NODES * D_HID);      // fp8, 25.6 MB
    __hip_bfloat16* hb   = (__hip_bfloat16*)alloc((size_t)M_PAD * D_HID * 2);   // 51.2 MB
    unsigned short* sup2 = (unsigned short*)alloc((size_t)N_NODES * D_OUT * 2); // bf16, 12.8 MB
    int* offsets         = (int*)alloc((size_t)(N_NODES + 1) * 4);
    int* gcnt            = (int*)alloc((size_t)NB * 4);
    int* boff            = (int*)alloc((size_t)(NB + 1) * 4);
    int* gcur            = (int*)alloc((size_t)NB * 4);
    int2* edges          = (int2*)alloc((size_t)N_EDGES * 8);                   // 25.6 MB
    int2* bucketed       = (int2*)alloc((size_t)N_EDGES * 8);                   // 25.6 MB

    // ---- CSR build ----
    hipMemsetAsync(gcnt, 0, (size_t)NB * 4, stream);
    hist_bucket_kernel<<<NBLK_BIN, 256, 0, stream>>>(row, gcnt);
    scan_nb_kernel<<<1, 1024, 0, stream>>>(gcnt, boff, gcur, offsets);
    bin_kernel<<<NBLK_BIN, 256, 0, stream>>>(row, col, ew, gcur, bucketed);
    csr_kernel<<<NB, 256, 0, stream>>>(bucketed, boff, offsets, edges);

    // ---- weight casts ----
    cast_w1t_kernel<<<(D_IN * D_HID + 255) / 256, 256, 0, stream>>>(w1, w1t);
    cast_w2t_kernel<<<(D_HID * D_OUT + 255) / 256, 256, 0, stream>>>(w2, w2t);

    // ---- layer 1: sup1(fp8) = bf16(x) @ w1t^T ; hb = relu(agg + b1) ----
    gemm_bf16_kernel<128, 2, 2, 4, 4, true, 2><<<dim3(M_PAD / 128, D_HID / 128), 256, 0, stream>>>(
        x, w1t, sup1, D_IN, N_NODES, N_NODES, D_HID);
    agg1_kernel<<<M_PAD / 4, 256, 0, stream>>>((const uint2*)sup1, offsets, edges, b1, hb);

    // ---- layer 2: sup2(bf16) = hb @ w2t^T ; out = log_softmax(agg + b2) ----
    gemm_bf16_kernel<64, 4, 1, 2, 4, false, 1><<<dim3(M_PAD / 128, 1), 256, 0, stream>>>(
        hb, w2t, sup2, D_HID, N_NODES, M_PAD, D_OUT);
    agg2_softmax_kernel<<<(N_NODES + 3) / 4, 256, 0, stream>>>((const unsigned int*)sup2,
                                                               offsets, edges, b2, out);
}

// Round 5
// 721.719 us; speedup vs baseline: 1.0623x; 1.0086x over previous
//
#include <hip/hip_runtime.h>
#include <hip/hip_bf16.h>
#include <hip/hip_fp8.h>

#define N_NODES 100000
#define N_EDGES 3200000
#define D_IN 512
#define D_HID 256
#define D_OUT 64
#define M_PAD 100096  // 782 * 128

#define NB 782    // row buckets of 128 rows (row >> 7)
#define EPB 8192  // edges per binning block
#define NBLK_BIN ((N_EDGES + EPB - 1) / EPB)  // 391

typedef __attribute__((ext_vector_type(8))) short bf16x8;
typedef __attribute__((ext_vector_type(4))) float f32x4;
typedef __attribute__((ext_vector_type(2))) float f32x2;

__device__ __forceinline__ unsigned short f2bf(float f) {
    __hip_bfloat16 h = __float2bfloat16(f);
    return *reinterpret_cast<unsigned short*>(&h);
}
__device__ __forceinline__ float f8f(unsigned int byte) {  // fp8 e4m3 -> f32 (HW cvt on gfx950)
    __hip_fp8_e4m3 t;
    t.__x = (__hip_fp8_storage_t)byte;
    return (float)t;
}

__device__ __forceinline__ void acc4_fp8(float* a, float wv, unsigned int u) {
#if __has_builtin(__builtin_amdgcn_cvt_pk_f32_fp8)
    f32x2 p0 = __builtin_amdgcn_cvt_pk_f32_fp8(u, false);
    f32x2 p1 = __builtin_amdgcn_cvt_pk_f32_fp8(u, true);
    a[0] += wv * p0.x; a[1] += wv * p0.y;
    a[2] += wv * p1.x; a[3] += wv * p1.y;
#else
    a[0] += wv * f8f(u & 0xff);
    a[1] += wv * f8f((u >> 8) & 0xff);
    a[2] += wv * f8f((u >> 16) & 0xff);
    a[3] += wv * f8f(u >> 24);
#endif
}

// 16 x fp8 (uint4) -> 16 f32 multiply-accumulate with packed HW converts.
__device__ __forceinline__ void acc16_fp8(float* a, float wv, uint4 v) {
    acc4_fp8(a + 0, wv, v.x);
    acc4_fp8(a + 4, wv, v.y);
    acc4_fp8(a + 8, wv, v.z);
    acc4_fp8(a + 12, wv, v.w);
}

// async global->LDS, 16B per lane. Dest must be linear (base + lane*16).
__device__ __forceinline__ void gload_lds16(const void* g, void* l) {
    __builtin_amdgcn_global_load_lds(
        (const __attribute__((address_space(1))) unsigned int*)g,
        (__attribute__((address_space(3))) unsigned int*)l, 16, 0, 0);
}

// ---------------- small casts ----------------

__global__ void cast_w1t_kernel(const float* __restrict__ w1, __hip_bfloat16* __restrict__ w1t) {
    int i = blockIdx.x * 256 + threadIdx.x;
    if (i >= D_IN * D_HID) return;
    int k = i / D_HID, n = i % D_HID;
    w1t[n * D_IN + k] = __float2bfloat16(w1[i]);
}

__global__ void cast_w2t_kernel(const float* __restrict__ w2, __hip_bfloat16* __restrict__ w2t) {
    int i = blockIdx.x * 256 + threadIdx.x;
    if (i >= D_HID * D_OUT) return;
    int k = i / D_OUT, n = i % D_OUT;
    w2t[n * D_HID + k] = __float2bfloat16(w2[i]);
}

// ---------------- CSR build (two-phase binned) ----------------

__global__ __launch_bounds__(256) void hist_bucket_kernel(const int* __restrict__ row,
                                                          int* __restrict__ gcnt) {
    __shared__ int cnt[NB];
    for (int i = threadIdx.x; i < NB; i += 256) cnt[i] = 0;
    __syncthreads();
    int base = blockIdx.x * EPB;
    for (int i = threadIdx.x; i < EPB; i += 256) {
        int e = base + i;
        if (e < N_EDGES) atomicAdd(&cnt[row[e] >> 7], 1);
    }
    __syncthreads();
    for (int i = threadIdx.x; i < NB; i += 256) {
        int c = cnt[i];
        if (c) atomicAdd(&gcnt[i], c);
    }
}

__global__ void scan_nb_kernel(const int* __restrict__ gcnt, int* __restrict__ boff,
                               int* __restrict__ gcur, int* __restrict__ offsets) {
    __shared__ int smem[1024];
    int t = threadIdx.x;
    int v = (t < NB) ? gcnt[t] : 0;
    smem[t] = v;
    __syncthreads();
    for (int off = 1; off < 1024; off <<= 1) {
        int u = (t >= off) ? smem[t - off] : 0;
        __syncthreads();
        smem[t] += u;
        __syncthreads();
    }
    int excl = smem[t] - v;
    if (t < NB) { boff[t] = excl; gcur[t] = excl; }
    if (t == 1023) boff[NB] = smem[1023];
    if (t == 0) offsets[N_NODES] = N_EDGES;
}

__global__ __launch_bounds__(256) void bin_kernel(const int* __restrict__ row,
                                                  const int* __restrict__ col,
                                                  const float* __restrict__ ew,
                                                  int* __restrict__ gcur,
                                                  int2* __restrict__ bucketed) {
    __shared__ int cnt[NB];
    __shared__ int cur[NB];
    for (int i = threadIdx.x; i < NB; i += 256) cnt[i] = 0;
    __syncthreads();
    int base = blockIdx.x * EPB;
    for (int i = threadIdx.x; i < EPB; i += 256) {
        int e = base + i;
        if (e < N_EDGES) atomicAdd(&cnt[row[e] >> 7], 1);
    }
    __syncthreads();
    for (int i = threadIdx.x; i < NB; i += 256) {
        int c = cnt[i];
        cur[i] = c ? atomicAdd(&gcur[i], c) : 0;
    }
    __syncthreads();
    for (int i = threadIdx.x; i < EPB; i += 256) {
        int e = base + i;
        if (e < N_EDGES) {
            int r = row[e];
            int b = r >> 7;
            int pos = atomicAdd(&cur[b], 1);
            bucketed[pos] = make_int2((col[e] << 7) | (r & 127), __float_as_int(ew[e]));
        }
    }
}

__global__ __launch_bounds__(256) void csr_kernel(const int2* __restrict__ bucketed,
                                                  const int* __restrict__ boff,
                                                  int* __restrict__ offsets,
                                                  int2* __restrict__ edges) {
    __shared__ int rcnt[128];
    __shared__ int sc[128];
    __shared__ int rcur[128];
    int b = blockIdx.x;
    int t = threadIdx.x;
    int s = boff[b], e2 = boff[b + 1];
    if (t < 128) rcnt[t] = 0;
    __syncthreads();
    for (int i = s + t; i < e2; i += 256) atomicAdd(&rcnt[bucketed[i].x & 127], 1);
    __syncthreads();
    if (t < 128) sc[t] = rcnt[t];
    __syncthreads();
    for (int off = 1; off < 128; off <<= 1) {
        int u = 0;
        if (t < 128 && t >= off) u = sc[t - off];
        __syncthreads();
        if (t < 128) sc[t] += u;
        __syncthreads();
    }
    if (t < 128) {
        int excl = sc[t] - rcnt[t];
        rcur[t] = excl;
        int rglob = b * 128 + t;
        if (rglob < N_NODES) offsets[rglob] = s + excl;
    }
    __syncthreads();
    for (int i = s + t; i < e2; i += 256) {
        int2 p = bucketed[i];
        int r = p.x & 127;
        int pos = atomicAdd(&rcur[r], 1);
        edges[s + pos] = make_int2(p.x >> 7, p.y);
    }
}

// ---------------- MFMA GEMM (m97 structure: global_load_lds + XOR swizzle) ----------------
// C[M x N] = A[M x K] * Bt[N x K]^T. A either fp32 (converted at LDS->frag read) or bf16.
// LDS is LINEAR (global_load_lds requirement); bank-conflict swizzle is applied by
// pre-swizzling the GLOBAL source address (m173 pattern) and un-swizzling on ds_read.
// OUT_MODE: 0 = fp32, 1 = bf16, 2 = fp8 e4m3.

template <int BN, int WROWS, int WCOLS, int MT, int NT, bool A_F32, int OUT_MODE>
__global__ __launch_bounds__(256) void gemm_bf16_kernel(
    const void* __restrict__ Av, const __hip_bfloat16* __restrict__ Bt,
    void* __restrict__ Cv, int K, int Mvalid, int Mload, int Nld) {
    constexpr int BM = 128;
    constexpr int BK = 32;
    constexpr int ABYTES = BM * BK * (A_F32 ? 4 : 2);
    constexpr int BBYTES = BN * BK * 2;
    __shared__ __align__(16) unsigned char As[ABYTES];
    __shared__ __align__(16) unsigned char Bs[BBYTES];

    const int tid = threadIdx.x;
    const int m0 = blockIdx.x * BM;
    const int n0 = blockIdx.y * BN;
    const int w = tid >> 6, lane = tid & 63;
    const int wr = w % WROWS, wc = w / WROWS;
    const int mbase = wr * MT * 16, nbase = wc * NT * 16;
    const int quad = lane >> 4, l16 = lane & 15;

    f32x4 acc[MT][NT] = {};

    constexpr int AISS = ABYTES / (256 * 16);
    constexpr int BISS = BBYTES / (256 * 16);

    for (int k0 = 0; k0 < K; k0 += BK) {
        // ---- stage A via global_load_lds (linear dest, pre-swizzled source) ----
#pragma unroll
        for (int c = 0; c < AISS; ++c) {
            int idx = c * 256 + tid;
            if constexpr (A_F32) {
                int r = idx >> 3, slot = idx & 7;  // fp32 row = 128B = 8 x 16B slots
                if (m0 + r < Mload) {
                    const float* src = (const float*)Av + (size_t)(m0 + r) * K + k0 +
                                       ((slot ^ (r & 7)) << 2);
                    gload_lds16(src, As + idx * 16);
                }
            } else {
                int r = idx >> 2, slot = idx & 3;  // bf16 row = 64B = 4 x 16B slots
                if (m0 + r < Mload) {
                    const __hip_bfloat16* src = (const __hip_bfloat16*)Av +
                                                (size_t)(m0 + r) * K + k0 +
                                                ((slot ^ (r & 3)) << 3);
                    gload_lds16(src, As + idx * 16);
                }
            }
        }
        // ---- stage B ----
#pragma unroll
        for (int c = 0; c < BISS; ++c) {
            int idx = c * 256 + tid;
            int r = idx >> 2, slot = idx & 3;
            const __hip_bfloat16* src = Bt + (size_t)(n0 + r) * K + k0 +
                                        ((slot ^ (r & 3)) << 3);
            gload_lds16(src, Bs + idx * 16);
        }
        __syncthreads();  // compiler emits vmcnt(0) drain before s_barrier

        bf16x8 af[MT], bfr[NT];
#pragma unroll
        for (int mt = 0; mt < MT; ++mt) {
            int r = mbase + mt * 16 + l16;
            if constexpr (A_F32) {
                const float4* rowp = (const float4*)(As + r * 128);
                int sw = r & 7;
                float4 f0 = rowp[(quad * 2) ^ sw];
                float4 f1 = rowp[(quad * 2 + 1) ^ sw];
                union { bf16x8 v; unsigned short u[8]; } o;
                o.u[0] = f2bf(f0.x); o.u[1] = f2bf(f0.y);
                o.u[2] = f2bf(f0.z); o.u[3] = f2bf(f0.w);
                o.u[4] = f2bf(f1.x); o.u[5] = f2bf(f1.y);
                o.u[6] = f2bf(f1.z); o.u[7] = f2bf(f1.w);
                af[mt] = o.v;
            } else {
                af[mt] = *(const bf16x8*)(As + r * 64 + ((quad ^ (r & 3)) * 16));
            }
        }
#pragma unroll
        for (int nt = 0; nt < NT; ++nt) {
            int r = nbase + nt * 16 + l16;
            bfr[nt] = *(const bf16x8*)(Bs + r * 64 + ((quad ^ (r & 3)) * 16));
        }
#pragma unroll
        for (int mt = 0; mt < MT; ++mt)
#pragma unroll
            for (int nt = 0; nt < NT; ++nt)
                acc[mt][nt] = __builtin_amdgcn_mfma_f32_16x16x32_bf16(af[mt], bfr[nt],
                                                                      acc[mt][nt], 0, 0, 0);
        __syncthreads();
    }

#pragma unroll
    for (int mt = 0; mt < MT; ++mt)
#pragma unroll
        for (int nt = 0; nt < NT; ++nt)
#pragma unroll
            for (int r = 0; r < 4; ++r) {
                int rowi = m0 + mbase + mt * 16 + quad * 4 + r;
                int coli = n0 + nbase + nt * 16 + l16;
                if (rowi < Mvalid) {
                    if constexpr (OUT_MODE == 0) {
                        ((float*)Cv)[(size_t)rowi * Nld + coli] = acc[mt][nt][r];
                    } else if constexpr (OUT_MODE == 1) {
                        ((__hip_bfloat16*)Cv)[(size_t)rowi * Nld + coli] =
                            __float2bfloat16(acc[mt][nt][r]);
                    } else {
                        __hip_fp8_e4m3 q(acc[mt][nt][r]);
                        ((unsigned char*)Cv)[(size_t)rowi * Nld + coli] = q.__x;
                    }
                }
            }
}

// ---------------- aggregation ----------------

// layer 1: hb = relu(agg(sup1 fp8) + b1) -> bf16; zero-fills pad rows.
// One wave per node, 4 edges per wave (one per 16-lane quad); each lane owns 16 dims
// (uint4 = 16 fp8). x4 unroll => 16 edges in flight; edge-meta prefetched 1 iter ahead.
__global__ __launch_bounds__(256) void agg1_kernel(
    const uint4* __restrict__ sup,  // fp8 [N_NODES][256] as uint4[N_NODES][16]
    const int* __restrict__ offsets, const int2* __restrict__ edges,
    const float* __restrict__ b1, __hip_bfloat16* __restrict__ hb) {
    int n = blockIdx.x * 4 + (threadIdx.x >> 6);
    int lane = threadIdx.x & 63;
    int q = lane >> 4;    // edge partition 0..3
    int l16 = lane & 15;  // dim group: dims [l16*16, l16*16+16)
    if (n >= M_PAD) return;
    if (n >= N_NODES) {
        // zero-fill pad row: 256 bf16 = 512B; 64 lanes x 8B
        *reinterpret_cast<uint2*>(&hb[(size_t)n * D_HID + lane * 4]) = uint2{0, 0};
        return;
    }
    int s = offsets[n], e2 = offsets[n + 1];
    int deg = e2 - s;
    int T = deg >> 4;  // full 16-edge iterations (wave-uniform)
    float a[16] = {};
    int e = s;
    int2 c0, c1, c2, c3;
    if (T > 0) {
        c0 = edges[e + q];
        c1 = edges[e + q + 4];
        c2 = edges[e + q + 8];
        c3 = edges[e + q + 12];
    }
    for (int t = 0; t < T; ++t) {
        uint4 v0 = sup[(size_t)c0.x * 16 + l16];
        uint4 v1 = sup[(size_t)c1.x * 16 + l16];
        uint4 v2 = sup[(size_t)c2.x * 16 + l16];
        uint4 v3 = sup[(size_t)c3.x * 16 + l16];
        float w0 = __int_as_float(c0.y), w1 = __int_as_float(c1.y);
        float w2 = __int_as_float(c2.y), w3 = __int_as_float(c3.y);
        e += 16;
        if (t + 1 < T) {  // prefetch next metas (independent of gathers in flight)
            c0 = edges[e + q];
            c1 = edges[e + q + 4];
            c2 = edges[e + q + 8];
            c3 = edges[e + q + 12];
        }
        acc16_fp8(a, w0, v0);
        acc16_fp8(a, w1, v1);
        acc16_fp8(a, w2, v2);
        acc16_fp8(a, w3, v3);
    }
    // tail: per-quad strided, no wasted gathers
    for (int ee = e + q; ee < e2; ee += 4) {
        int2 m = edges[ee];
        uint4 v = sup[(size_t)m.x * 16 + l16];
        acc16_fp8(a, __int_as_float(m.y), v);
    }
    // combine the 4 quad partitions (all lanes end with full sums)
#pragma unroll
    for (int i = 0; i < 16; ++i) {
        a[i] += __shfl_xor(a[i], 16, 64);
        a[i] += __shfl_xor(a[i], 32, 64);
    }
    if (q < 2) {  // 32 lanes write 16B each: quad q writes dims [l16*16+q*8, +8)
        float4 bbA = reinterpret_cast<const float4*>(b1)[l16 * 4 + q * 2];
        float4 bbB = reinterpret_cast<const float4*>(b1)[l16 * 4 + q * 2 + 1];
        int base = q * 8;
        union { uint4 u4; unsigned short us[8]; } o;
        o.us[0] = f2bf(fmaxf(a[base + 0] + bbA.x, 0.f));
        o.us[1] = f2bf(fmaxf(a[base + 1] + bbA.y, 0.f));
        o.us[2] = f2bf(fmaxf(a[base + 2] + bbA.z, 0.f));
        o.us[3] = f2bf(fmaxf(a[base + 3] + bbA.w, 0.f));
        o.us[4] = f2bf(fmaxf(a[base + 4] + bbB.x, 0.f));
        o.us[5] = f2bf(fmaxf(a[base + 5] + bbB.y, 0.f));
        o.us[6] = f2bf(fmaxf(a[base + 6] + bbB.z, 0.f));
        o.us[7] = f2bf(fmaxf(a[base + 7] + bbB.w, 0.f));
        *reinterpret_cast<uint4*>(&hb[(size_t)n * D_HID + l16 * 16 + q * 8]) = o.u4;
    }
}

// layer 2: agg(sup2 bf16) + b2, log_softmax over 64 dims.
// One wave per node, 2 edges per wave; each lane owns 2 dims (uint = 2 bf16).
__global__ __launch_bounds__(256) void agg2_softmax_kernel(
    const unsigned int* __restrict__ sup2v,  // bf16 [N_NODES][64] as uint[N_NODES][32]
    const int* __restrict__ offsets, const int2* __restrict__ edges,
    const float* __restrict__ b2, float* __restrict__ out) {
    int n = blockIdx.x * 4 + (threadIdx.x >> 6);
    int lane = threadIdx.x & 63;
    int half = lane >> 5;
    int l32 = lane & 31;
    if (n >= N_NODES) return;
    int s = offsets[n], e2 = offsets[n + 1];
    float a0 = 0.f, a1 = 0.f;
    int e = s + half;
    for (; e + 6 < e2; e += 8) {
        int2 m0 = edges[e], m1 = edges[e + 2], m2 = edges[e + 4], m3 = edges[e + 6];
        unsigned v0 = sup2v[(size_t)m0.x * 32 + l32];
        unsigned v1 = sup2v[(size_t)m1.x * 32 + l32];
        unsigned v2 = sup2v[(size_t)m2.x * 32 + l32];
        unsigned v3 = sup2v[(size_t)m3.x * 32 + l32];
        float w0 = __int_as_float(m0.y), w1 = __int_as_float(m1.y);
        float w2 = __int_as_float(m2.y), w3 = __int_as_float(m3.y);
        a0 += w0 * __uint_as_float(v0 << 16);
        a1 += w0 * __uint_as_float(v0 & 0xffff0000u);
        a0 += w1 * __uint_as_float(v1 << 16);
        a1 += w1 * __uint_as_float(v1 & 0xffff0000u);
        a0 += w2 * __uint_as_float(v2 << 16);
        a1 += w2 * __uint_as_float(v2 & 0xffff0000u);
        a0 += w3 * __uint_as_float(v3 << 16);
        a1 += w3 * __uint_as_float(v3 & 0xffff0000u);
    }
    for (; e < e2; e += 2) {
        int2 m = edges[e];
        unsigned v = sup2v[(size_t)m.x * 32 + l32];
        float wv = __int_as_float(m.y);
        a0 += wv * __uint_as_float(v << 16);
        a1 += wv * __uint_as_float(v & 0xffff0000u);
    }
    // combine half-wave partitions (both halves end with full sums)
    a0 += __shfl_xor(a0, 32, 64);
    a1 += __shfl_xor(a1, 32, 64);
    float2 bb = reinterpret_cast<const float2*>(b2)[l32];
    a0 += bb.x;
    a1 += bb.y;
    float m = fmaxf(a0, a1);
#pragma unroll
    for (int o = 16; o > 0; o >>= 1) m = fmaxf(m, __shfl_xor(m, o, 64));
    float ssum = __expf(a0 - m) + __expf(a1 - m);
#pragma unroll
    for (int o = 16; o > 0; o >>= 1) ssum += __shfl_xor(ssum, o, 64);
    if (half == 0) {
        float lse = m + __logf(ssum);
        float2 r;
        r.x = a0 - lse;
        r.y = a1 - lse;
        reinterpret_cast<float2*>(out)[(size_t)n * 32 + l32] = r;
    }
}

// ---------------- launch ----------------

extern "C" void kernel_launch(void* const* d_in, const int* in_sizes, int n_in,
                              void* d_out, int out_size, void* d_ws, size_t ws_size,
                              hipStream_t stream) {
    const float* x  = (const float*)d_in[0];
    const int* row  = (const int*)d_in[1];
    const int* col  = (const int*)d_in[2];
    const float* ew = (const float*)d_in[3];
    const float* w1 = (const float*)d_in[4];
    const float* b1 = (const float*)d_in[5];
    const float* w2 = (const float*)d_in[6];
    const float* b2 = (const float*)d_in[7];
    float* out = (float*)d_out;

    char* ws = (char*)d_ws;
    size_t off = 0;
    auto alloc = [&](size_t bytes) -> void* {
        void* p = ws + off;
        off = (off + bytes + 255) & ~(size_t)255;
        return p;
    };

    __hip_bfloat16* w1t  = (__hip_bfloat16*)alloc((size_t)D_HID * D_IN * 2);
    __hip_bfloat16* w2t  = (__hip_bfloat16*)alloc((size_t)D_OUT * D_HID * 2);
    unsigned char* sup1  = (unsigned char*)alloc((size_t)N_NODES * D_HID);      // fp8, 25.6 MB
    __hip_bfloat16* hb   = (__hip_bfloat16*)alloc((size_t)M_PAD * D_HID * 2);   // 51.2 MB
    unsigned short* sup2 = (unsigned short*)alloc((size_t)N_NODES * D_OUT * 2); // bf16, 12.8 MB
    int* offsets         = (int*)alloc((size_t)(N_NODES + 1) * 4);
    int* gcnt            = (int*)alloc((size_t)NB * 4);
    int* boff            = (int*)alloc((size_t)(NB + 1) * 4);
    int* gcur            = (int*)alloc((size_t)NB * 4);
    int2* edges          = (int2*)alloc((size_t)N_EDGES * 8);                   // 25.6 MB
    int2* bucketed       = (int2*)alloc((size_t)N_EDGES * 8);                   // 25.6 MB

    // ---- CSR build ----
    hipMemsetAsync(gcnt, 0, (size_t)NB * 4, stream);
    hist_bucket_kernel<<<NBLK_BIN, 256, 0, stream>>>(row, gcnt);
    scan_nb_kernel<<<1, 1024, 0, stream>>>(gcnt, boff, gcur, offsets);
    bin_kernel<<<NBLK_BIN, 256, 0, stream>>>(row, col, ew, gcur, bucketed);
    csr_kernel<<<NB, 256, 0, stream>>>(bucketed, boff, offsets, edges);

    // ---- weight casts ----
    cast_w1t_kernel<<<(D_IN * D_HID + 255) / 256, 256, 0, stream>>>(w1, w1t);
    cast_w2t_kernel<<<(D_HID * D_OUT + 255) / 256, 256, 0, stream>>>(w2, w2t);

    // ---- layer 1: sup1(fp8) = bf16(x) @ w1t^T ; hb = relu(agg + b1) ----
    gemm_bf16_kernel<128, 2, 2, 4, 4, true, 2><<<dim3(M_PAD / 128, D_HID / 128), 256, 0, stream>>>(
        x, w1t, sup1, D_IN, N_NODES, N_NODES, D_HID);
    agg1_kernel<<<M_PAD / 4, 256, 0, stream>>>((const uint4*)sup1, offsets, edges, b1, hb);

    // ---- layer 2: sup2(bf16) = hb @ w2t^T ; out = log_softmax(agg + b2) ----
    gemm_bf16_kernel<64, 4, 1, 2, 4, false, 1><<<dim3(M_PAD / 128, 1), 256, 0, stream>>>(
        hb, w2t, sup2, D_HID, N_NODES, M_PAD, D_OUT);
    agg2_softmax_kernel<<<(N_NODES + 3) / 4, 256, 0, stream>>>((const unsigned int*)sup2,
                                                               offsets, edges, b2, out);
}

// Round 6
// 701.505 us; speedup vs baseline: 1.0929x; 1.0288x over previous
//
#include <hip/hip_runtime.h>
#include <hip/hip_bf16.h>
#include <hip/hip_fp8.h>

#define N_NODES 100000
#define N_EDGES 3200000
#define D_IN 512
#define D_HID 256
#define D_OUT 64
#define M_PAD 100096  // 782 * 128

#define NB 782    // row buckets of 128 rows (row >> 7)
#define EPB 8192  // edges per binning block
#define NBLK_BIN ((N_EDGES + EPB - 1) / EPB)  // 391

typedef __attribute__((ext_vector_type(8))) short bf16x8;
typedef __attribute__((ext_vector_type(4))) float f32x4;
typedef __attribute__((ext_vector_type(2))) float f32x2;

__device__ __forceinline__ unsigned short f2bf(float f) {
    __hip_bfloat16 h = __float2bfloat16(f);
    return *reinterpret_cast<unsigned short*>(&h);
}
// HW packed f32x2 -> 2x bf16 in one inst (no builtin on gfx950; inline asm per T12)
__device__ __forceinline__ unsigned int cvt_pk_bf16(float lo, float hi) {
    unsigned int r;
    asm("v_cvt_pk_bf16_f32 %0, %1, %2" : "=v"(r) : "v"(lo), "v"(hi));
    return r;
}
__device__ __forceinline__ float f8f(unsigned int byte) {  // fp8 e4m3 -> f32 (HW cvt on gfx950)
    __hip_fp8_e4m3 t;
    t.__x = (__hip_fp8_storage_t)byte;
    return (float)t;
}

__device__ __forceinline__ void acc4_fp8(float* a, float wv, unsigned int u) {
#if __has_builtin(__builtin_amdgcn_cvt_pk_f32_fp8)
    f32x2 p0 = __builtin_amdgcn_cvt_pk_f32_fp8(u, false);
    f32x2 p1 = __builtin_amdgcn_cvt_pk_f32_fp8(u, true);
    a[0] += wv * p0.x; a[1] += wv * p0.y;
    a[2] += wv * p1.x; a[3] += wv * p1.y;
#else
    a[0] += wv * f8f(u & 0xff);
    a[1] += wv * f8f((u >> 8) & 0xff);
    a[2] += wv * f8f((u >> 16) & 0xff);
    a[3] += wv * f8f(u >> 24);
#endif
}

// 16 x fp8 (uint4) -> 16 f32 multiply-accumulate with packed HW converts.
__device__ __forceinline__ void acc16_fp8(float* a, float wv, uint4 v) {
    acc4_fp8(a + 0, wv, v.x);
    acc4_fp8(a + 4, wv, v.y);
    acc4_fp8(a + 8, wv, v.z);
    acc4_fp8(a + 12, wv, v.w);
}

// async global->LDS, 16B per lane. Dest must be linear (base + lane*16).
__device__ __forceinline__ void gload_lds16(const void* g, void* l) {
    __builtin_amdgcn_global_load_lds(
        (const __attribute__((address_space(1))) unsigned int*)g,
        (__attribute__((address_space(3))) unsigned int*)l, 16, 0, 0);
}

// ---------------- small casts ----------------

__global__ void cast_w1t_kernel(const float* __restrict__ w1, __hip_bfloat16* __restrict__ w1t) {
    int i = blockIdx.x * 256 + threadIdx.x;
    if (i >= D_IN * D_HID) return;
    int k = i / D_HID, n = i % D_HID;
    w1t[n * D_IN + k] = __float2bfloat16(w1[i]);
}

__global__ void cast_w2t_kernel(const float* __restrict__ w2, __hip_bfloat16* __restrict__ w2t) {
    int i = blockIdx.x * 256 + threadIdx.x;
    if (i >= D_HID * D_OUT) return;
    int k = i / D_OUT, n = i % D_OUT;
    w2t[n * D_HID + k] = __float2bfloat16(w2[i]);
}

// ---------------- CSR build (two-phase binned) ----------------

__global__ __launch_bounds__(256) void hist_bucket_kernel(const int* __restrict__ row,
                                                          int* __restrict__ gcnt) {
    __shared__ int cnt[NB];
    for (int i = threadIdx.x; i < NB; i += 256) cnt[i] = 0;
    __syncthreads();
    int base = blockIdx.x * EPB;
    for (int i = threadIdx.x; i < EPB; i += 256) {
        int e = base + i;
        if (e < N_EDGES) atomicAdd(&cnt[row[e] >> 7], 1);
    }
    __syncthreads();
    for (int i = threadIdx.x; i < NB; i += 256) {
        int c = cnt[i];
        if (c) atomicAdd(&gcnt[i], c);
    }
}

__global__ void scan_nb_kernel(const int* __restrict__ gcnt, int* __restrict__ boff,
                               int* __restrict__ gcur, int* __restrict__ offsets) {
    __shared__ int smem[1024];
    int t = threadIdx.x;
    int v = (t < NB) ? gcnt[t] : 0;
    smem[t] = v;
    __syncthreads();
    for (int off = 1; off < 1024; off <<= 1) {
        int u = (t >= off) ? smem[t - off] : 0;
        __syncthreads();
        smem[t] += u;
        __syncthreads();
    }
    int excl = smem[t] - v;
    if (t < NB) { boff[t] = excl; gcur[t] = excl; }
    if (t == 1023) boff[NB] = smem[1023];
    if (t == 0) offsets[N_NODES] = N_EDGES;
}

__global__ __launch_bounds__(256) void bin_kernel(const int* __restrict__ row,
                                                  const int* __restrict__ col,
                                                  const float* __restrict__ ew,
                                                  int* __restrict__ gcur,
                                                  int2* __restrict__ bucketed) {
    __shared__ int cnt[NB];
    __shared__ int cur[NB];
    for (int i = threadIdx.x; i < NB; i += 256) cnt[i] = 0;
    __syncthreads();
    int base = blockIdx.x * EPB;
    for (int i = threadIdx.x; i < EPB; i += 256) {
        int e = base + i;
        if (e < N_EDGES) atomicAdd(&cnt[row[e] >> 7], 1);
    }
    __syncthreads();
    for (int i = threadIdx.x; i < NB; i += 256) {
        int c = cnt[i];
        cur[i] = c ? atomicAdd(&gcur[i], c) : 0;
    }
    __syncthreads();
    for (int i = threadIdx.x; i < EPB; i += 256) {
        int e = base + i;
        if (e < N_EDGES) {
            int r = row[e];
            int b = r >> 7;
            int pos = atomicAdd(&cur[b], 1);
            bucketed[pos] = make_int2((col[e] << 7) | (r & 127), __float_as_int(ew[e]));
        }
    }
}

__global__ __launch_bounds__(256) void csr_kernel(const int2* __restrict__ bucketed,
                                                  const int* __restrict__ boff,
                                                  int* __restrict__ offsets,
                                                  int2* __restrict__ edges) {
    __shared__ int rcnt[128];
    __shared__ int sc[128];
    __shared__ int rcur[128];
    int b = blockIdx.x;
    int t = threadIdx.x;
    int s = boff[b], e2 = boff[b + 1];
    if (t < 128) rcnt[t] = 0;
    __syncthreads();
    for (int i = s + t; i < e2; i += 256) atomicAdd(&rcnt[bucketed[i].x & 127], 1);
    __syncthreads();
    if (t < 128) sc[t] = rcnt[t];
    __syncthreads();
    for (int off = 1; off < 128; off <<= 1) {
        int u = 0;
        if (t < 128 && t >= off) u = sc[t - off];
        __syncthreads();
        if (t < 128) sc[t] += u;
        __syncthreads();
    }
    if (t < 128) {
        int excl = sc[t] - rcnt[t];
        rcur[t] = excl;
        int rglob = b * 128 + t;
        if (rglob < N_NODES) offsets[rglob] = s + excl;
    }
    __syncthreads();
    for (int i = s + t; i < e2; i += 256) {
        int2 p = bucketed[i];
        int r = p.x & 127;
        int pos = atomicAdd(&rcur[r], 1);
        edges[s + pos] = make_int2(p.x >> 7, p.y);
    }
}

// ---------------- MFMA GEMM (m97 structure: global_load_lds + XOR swizzle) ----------------
// C[M x N] = A[M x K] * Bt[N x K]^T. A either fp32 (converted at LDS->frag read via
// v_cvt_pk_bf16_f32) or bf16. LDS is LINEAR (global_load_lds requirement); bank-conflict
// swizzle via pre-swizzled GLOBAL source (m173) + un-swizzle on ds_read.
// OUT_MODE: 0 = fp32, 1 = bf16, 2 = fp8 e4m3.

template <int BN, int WROWS, int WCOLS, int MT, int NT, bool A_F32, int OUT_MODE>
__global__ __launch_bounds__(256) void gemm_bf16_kernel(
    const void* __restrict__ Av, const __hip_bfloat16* __restrict__ Bt,
    void* __restrict__ Cv, int K, int Mvalid, int Mload, int Nld) {
    constexpr int BM = 128;
    constexpr int BK = 32;
    constexpr int ABYTES = BM * BK * (A_F32 ? 4 : 2);
    constexpr int BBYTES = BN * BK * 2;
    __shared__ __align__(16) unsigned char As[ABYTES];
    __shared__ __align__(16) unsigned char Bs[BBYTES];

    const int tid = threadIdx.x;
    const int m0 = blockIdx.x * BM;
    const int n0 = blockIdx.y * BN;
    const int w = tid >> 6, lane = tid & 63;
    const int wr = w % WROWS, wc = w / WROWS;
    const int mbase = wr * MT * 16, nbase = wc * NT * 16;
    const int quad = lane >> 4, l16 = lane & 15;

    f32x4 acc[MT][NT] = {};

    constexpr int AISS = ABYTES / (256 * 16);
    constexpr int BISS = BBYTES / (256 * 16);

    for (int k0 = 0; k0 < K; k0 += BK) {
        // ---- stage A via global_load_lds (linear dest, pre-swizzled source) ----
#pragma unroll
        for (int c = 0; c < AISS; ++c) {
            int idx = c * 256 + tid;
            if constexpr (A_F32) {
                int r = idx >> 3, slot = idx & 7;  // fp32 row = 128B = 8 x 16B slots
                if (m0 + r < Mload) {
                    const float* src = (const float*)Av + (size_t)(m0 + r) * K + k0 +
                                       ((slot ^ (r & 7)) << 2);
                    gload_lds16(src, As + idx * 16);
                }
            } else {
                int r = idx >> 2, slot = idx & 3;  // bf16 row = 64B = 4 x 16B slots
                if (m0 + r < Mload) {
                    const __hip_bfloat16* src = (const __hip_bfloat16*)Av +
                                                (size_t)(m0 + r) * K + k0 +
                                                ((slot ^ (r & 3)) << 3);
                    gload_lds16(src, As + idx * 16);
                }
            }
        }
        // ---- stage B ----
#pragma unroll
        for (int c = 0; c < BISS; ++c) {
            int idx = c * 256 + tid;
            int r = idx >> 2, slot = idx & 3;
            const __hip_bfloat16* src = Bt + (size_t)(n0 + r) * K + k0 +
                                        ((slot ^ (r & 3)) << 3);
            gload_lds16(src, Bs + idx * 16);
        }
        __syncthreads();  // compiler emits vmcnt(0) drain before s_barrier

        bf16x8 af[MT], bfr[NT];
#pragma unroll
        for (int mt = 0; mt < MT; ++mt) {
            int r = mbase + mt * 16 + l16;
            if constexpr (A_F32) {
                const float4* rowp = (const float4*)(As + r * 128);
                int sw = r & 7;
                float4 f0 = rowp[(quad * 2) ^ sw];
                float4 f1 = rowp[(quad * 2 + 1) ^ sw];
                union { bf16x8 v; unsigned int u[4]; } o;
                o.u[0] = cvt_pk_bf16(f0.x, f0.y);
                o.u[1] = cvt_pk_bf16(f0.z, f0.w);
                o.u[2] = cvt_pk_bf16(f1.x, f1.y);
                o.u[3] = cvt_pk_bf16(f1.z, f1.w);
                af[mt] = o.v;
            } else {
                af[mt] = *(const bf16x8*)(As + r * 64 + ((quad ^ (r & 3)) * 16));
            }
        }
#pragma unroll
        for (int nt = 0; nt < NT; ++nt) {
            int r = nbase + nt * 16 + l16;
            bfr[nt] = *(const bf16x8*)(Bs + r * 64 + ((quad ^ (r & 3)) * 16));
        }
#pragma unroll
        for (int mt = 0; mt < MT; ++mt)
#pragma unroll
            for (int nt = 0; nt < NT; ++nt)
                acc[mt][nt] = __builtin_amdgcn_mfma_f32_16x16x32_bf16(af[mt], bfr[nt],
                                                                      acc[mt][nt], 0, 0, 0);
        __syncthreads();
    }

#pragma unroll
    for (int mt = 0; mt < MT; ++mt)
#pragma unroll
        for (int nt = 0; nt < NT; ++nt)
#pragma unroll
            for (int r = 0; r < 4; ++r) {
                int rowi = m0 + mbase + mt * 16 + quad * 4 + r;
                int coli = n0 + nbase + nt * 16 + l16;
                if (rowi < Mvalid) {
                    if constexpr (OUT_MODE == 0) {
                        ((float*)Cv)[(size_t)rowi * Nld + coli] = acc[mt][nt][r];
                    } else if constexpr (OUT_MODE == 1) {
                        ((__hip_bfloat16*)Cv)[(size_t)rowi * Nld + coli] =
                            __float2bfloat16(acc[mt][nt][r]);
                    } else {
                        __hip_fp8_e4m3 q(acc[mt][nt][r]);
                        ((unsigned char*)Cv)[(size_t)rowi * Nld + coli] = q.__x;
                    }
                }
            }
}

// ---------------- aggregation ----------------

// layer 1: hb = relu(agg(sup1 fp8) + b1) -> bf16; zero-fills pad rows.
// One wave per node, 4 edges per wave (one per 16-lane quad); each lane owns 16 dims
// (uint4 = 16 fp8). x4 unroll => 16 edges in flight; edge-meta prefetched 1 iter ahead.
__global__ __launch_bounds__(256) void agg1_kernel(
    const uint4* __restrict__ sup,  // fp8 [N_NODES][256] as uint4[N_NODES][16]
    const int* __restrict__ offsets, const int2* __restrict__ edges,
    const float* __restrict__ b1, __hip_bfloat16* __restrict__ hb) {
    int n = blockIdx.x * 4 + (threadIdx.x >> 6);
    int lane = threadIdx.x & 63;
    int q = lane >> 4;    // edge partition 0..3
    int l16 = lane & 15;  // dim group: dims [l16*16, l16*16+16)
    if (n >= M_PAD) return;
    if (n >= N_NODES) {
        // zero-fill pad row: 256 bf16 = 512B; 64 lanes x 8B
        *reinterpret_cast<uint2*>(&hb[(size_t)n * D_HID + lane * 4]) = uint2{0, 0};
        return;
    }
    int s = offsets[n], e2 = offsets[n + 1];
    int deg = e2 - s;
    int T = deg >> 4;  // full 16-edge iterations (wave-uniform)
    float a[16] = {};
    int e = s;
    int2 c0, c1, c2, c3;
    if (T > 0) {
        c0 = edges[e + q];
        c1 = edges[e + q + 4];
        c2 = edges[e + q + 8];
        c3 = edges[e + q + 12];
    }
    for (int t = 0; t < T; ++t) {
        uint4 v0 = sup[(size_t)c0.x * 16 + l16];
        uint4 v1 = sup[(size_t)c1.x * 16 + l16];
        uint4 v2 = sup[(size_t)c2.x * 16 + l16];
        uint4 v3 = sup[(size_t)c3.x * 16 + l16];
        float w0 = __int_as_float(c0.y), w1 = __int_as_float(c1.y);
        float w2 = __int_as_float(c2.y), w3 = __int_as_float(c3.y);
        e += 16;
        if (t + 1 < T) {  // prefetch next metas (independent of gathers in flight)
            c0 = edges[e + q];
            c1 = edges[e + q + 4];
            c2 = edges[e + q + 8];
            c3 = edges[e + q + 12];
        }
        acc16_fp8(a, w0, v0);
        acc16_fp8(a, w1, v1);
        acc16_fp8(a, w2, v2);
        acc16_fp8(a, w3, v3);
    }
    // tail: per-quad strided, no wasted gathers
    for (int ee = e + q; ee < e2; ee += 4) {
        int2 m = edges[ee];
        uint4 v = sup[(size_t)m.x * 16 + l16];
        acc16_fp8(a, __int_as_float(m.y), v);
    }
    // combine the 4 quad partitions (all lanes end with full sums)
#pragma unroll
    for (int i = 0; i < 16; ++i) {
        a[i] += __shfl_xor(a[i], 16, 64);
        a[i] += __shfl_xor(a[i], 32, 64);
    }
    if (q < 2) {  // 32 lanes write 16B each: quad q writes dims [l16*16+q*8, +8)
        float4 bbA = reinterpret_cast<const float4*>(b1)[l16 * 4 + q * 2];
        float4 bbB = reinterpret_cast<const float4*>(b1)[l16 * 4 + q * 2 + 1];
        int base = q * 8;
        union { uint4 u4; unsigned short us[8]; } o;
        o.us[0] = f2bf(fmaxf(a[base + 0] + bbA.x, 0.f));
        o.us[1] = f2bf(fmaxf(a[base + 1] + bbA.y, 0.f));
        o.us[2] = f2bf(fmaxf(a[base + 2] + bbA.z, 0.f));
        o.us[3] = f2bf(fmaxf(a[base + 3] + bbA.w, 0.f));
        o.us[4] = f2bf(fmaxf(a[base + 4] + bbB.x, 0.f));
        o.us[5] = f2bf(fmaxf(a[base + 5] + bbB.y, 0.f));
        o.us[6] = f2bf(fmaxf(a[base + 6] + bbB.z, 0.f));
        o.us[7] = f2bf(fmaxf(a[base + 7] + bbB.w, 0.f));
        *reinterpret_cast<uint4*>(&hb[(size_t)n * D_HID + l16 * 16 + q * 8]) = o.u4;
    }
}

// layer 2: agg(sup2 bf16) + b2, log_softmax over 64 dims.
// One wave per node, 4 edges per wave (16-lane quads); each lane owns 4 dims
// (uint2 = 4 bf16). x4 unroll => 16 edges in flight; meta prefetch 1 iter ahead.
__global__ __launch_bounds__(256) void agg2_softmax_kernel(
    const uint2* __restrict__ sup2,  // bf16 [N_NODES][64] as uint2[N_NODES][16]
    const int* __restrict__ offsets, const int2* __restrict__ edges,
    const float* __restrict__ b2, float* __restrict__ out) {
    int n = blockIdx.x * 4 + (threadIdx.x >> 6);
    int lane = threadIdx.x & 63;
    int q = lane >> 4;    // edge partition 0..3
    int l16 = lane & 15;  // dims [l16*4, l16*4+4)
    if (n >= N_NODES) return;
    int s = offsets[n], e2 = offsets[n + 1];
    int T = (e2 - s) >> 4;
    float a0 = 0.f, a1 = 0.f, a2 = 0.f, a3 = 0.f;
    int e = s;
    int2 c0, c1, c2, c3;
    if (T > 0) {
        c0 = edges[e + q];
        c1 = edges[e + q + 4];
        c2 = edges[e + q + 8];
        c3 = edges[e + q + 12];
    }
    for (int t = 0; t < T; ++t) {
        uint2 v0 = sup2[(size_t)c0.x * 16 + l16];
        uint2 v1 = sup2[(size_t)c1.x * 16 + l16];
        uint2 v2 = sup2[(size_t)c2.x * 16 + l16];
        uint2 v3 = sup2[(size_t)c3.x * 16 + l16];
        float w0 = __int_as_float(c0.y), w1 = __int_as_float(c1.y);
        float w2 = __int_as_float(c2.y), w3 = __int_as_float(c3.y);
        e += 16;
        if (t + 1 < T) {
            c0 = edges[e + q];
            c1 = edges[e + q + 4];
            c2 = edges[e + q + 8];
            c3 = edges[e + q + 12];
        }
        a0 += w0 * __uint_as_float(v0.x << 16);
        a1 += w0 * __uint_as_float(v0.x & 0xffff0000u);
        a2 += w0 * __uint_as_float(v0.y << 16);
        a3 += w0 * __uint_as_float(v0.y & 0xffff0000u);
        a0 += w1 * __uint_as_float(v1.x << 16);
        a1 += w1 * __uint_as_float(v1.x & 0xffff0000u);
        a2 += w1 * __uint_as_float(v1.y << 16);
        a3 += w1 * __uint_as_float(v1.y & 0xffff0000u);
        a0 += w2 * __uint_as_float(v2.x << 16);
        a1 += w2 * __uint_as_float(v2.x & 0xffff0000u);
        a2 += w2 * __uint_as_float(v2.y << 16);
        a3 += w2 * __uint_as_float(v2.y & 0xffff0000u);
        a0 += w3 * __uint_as_float(v3.x << 16);
        a1 += w3 * __uint_as_float(v3.x & 0xffff0000u);
        a2 += w3 * __uint_as_float(v3.y << 16);
        a3 += w3 * __uint_as_float(v3.y & 0xffff0000u);
    }
    for (int ee = e + q; ee < e2; ee += 4) {
        int2 m = edges[ee];
        uint2 v = sup2[(size_t)m.x * 16 + l16];
        float wv = __int_as_float(m.y);
        a0 += wv * __uint_as_float(v.x << 16);
        a1 += wv * __uint_as_float(v.x & 0xffff0000u);
        a2 += wv * __uint_as_float(v.y << 16);
        a3 += wv * __uint_as_float(v.y & 0xffff0000u);
    }
    // combine the 4 quad partitions
    a0 += __shfl_xor(a0, 16, 64); a0 += __shfl_xor(a0, 32, 64);
    a1 += __shfl_xor(a1, 16, 64); a1 += __shfl_xor(a1, 32, 64);
    a2 += __shfl_xor(a2, 16, 64); a2 += __shfl_xor(a2, 32, 64);
    a3 += __shfl_xor(a3, 16, 64); a3 += __shfl_xor(a3, 32, 64);
    float4 bb = reinterpret_cast<const float4*>(b2)[l16];
    a0 += bb.x; a1 += bb.y; a2 += bb.z; a3 += bb.w;
    // softmax over 64 dims: each 16-lane quad independently holds all 64 dims
    float m = fmaxf(fmaxf(a0, a1), fmaxf(a2, a3));
#pragma unroll
    for (int o = 8; o > 0; o >>= 1) m = fmaxf(m, __shfl_xor(m, o, 64));
    float ssum = __expf(a0 - m) + __expf(a1 - m) + __expf(a2 - m) + __expf(a3 - m);
#pragma unroll
    for (int o = 8; o > 0; o >>= 1) ssum += __shfl_xor(ssum, o, 64);
    if (q == 0) {
        float lse = m + __logf(ssum);
        float4 r;
        r.x = a0 - lse; r.y = a1 - lse; r.z = a2 - lse; r.w = a3 - lse;
        reinterpret_cast<float4*>(out)[(size_t)n * 16 + l16] = r;
    }
}

// ---------------- launch ----------------

extern "C" void kernel_launch(void* const* d_in, const int* in_sizes, int n_in,
                              void* d_out, int out_size, void* d_ws, size_t ws_size,
                              hipStream_t stream) {
    const float* x  = (const float*)d_in[0];
    const int* row  = (const int*)d_in[1];
    const int* col  = (const int*)d_in[2];
    const float* ew = (const float*)d_in[3];
    const float* w1 = (const float*)d_in[4];
    const float* b1 = (const float*)d_in[5];
    const float* w2 = (const float*)d_in[6];
    const float* b2 = (const float*)d_in[7];
    float* out = (float*)d_out;

    char* ws = (char*)d_ws;
    size_t off = 0;
    auto alloc = [&](size_t bytes) -> void* {
        void* p = ws + off;
        off = (off + bytes + 255) & ~(size_t)255;
        return p;
    };

    __hip_bfloat16* w1t  = (__hip_bfloat16*)alloc((size_t)D_HID * D_IN * 2);
    __hip_bfloat16* w2t  = (__hip_bfloat16*)alloc((size_t)D_OUT * D_HID * 2);
    unsigned char* sup1  = (unsigned char*)alloc((size_t)N_NODES * D_HID);      // fp8, 25.6 MB
    __hip_bfloat16* hb   = (__hip_bfloat16*)alloc((size_t)M_PAD * D_HID * 2);   // 51.2 MB
    unsigned short* sup2 = (unsigned short*)alloc((size_t)N_NODES * D_OUT * 2); // bf16, 12.8 MB
    int* offsets         = (int*)alloc((size_t)(N_NODES + 1) * 4);
    int* gcnt            = (int*)alloc((size_t)NB * 4);
    int* boff            = (int*)alloc((size_t)(NB + 1) * 4);
    int* gcur            = (int*)alloc((size_t)NB * 4);
    int2* edges          = (int2*)alloc((size_t)N_EDGES * 8);                   // 25.6 MB
    int2* bucketed       = (int2*)alloc((size_t)N_EDGES * 8);                   // 25.6 MB

    // ---- CSR build ----
    hipMemsetAsync(gcnt, 0, (size_t)NB * 4, stream);
    hist_bucket_kernel<<<NBLK_BIN, 256, 0, stream>>>(row, gcnt);
    scan_nb_kernel<<<1, 1024, 0, stream>>>(gcnt, boff, gcur, offsets);
    bin_kernel<<<NBLK_BIN, 256, 0, stream>>>(row, col, ew, gcur, bucketed);
    csr_kernel<<<NB, 256, 0, stream>>>(bucketed, boff, offsets, edges);

    // ---- weight casts ----
    cast_w1t_kernel<<<(D_IN * D_HID + 255) / 256, 256, 0, stream>>>(w1, w1t);
    cast_w2t_kernel<<<(D_HID * D_OUT + 255) / 256, 256, 0, stream>>>(w2, w2t);

    // ---- layer 1: sup1(fp8) = bf16(x) @ w1t^T ; hb = relu(agg + b1) ----
    gemm_bf16_kernel<128, 2, 2, 4, 4, true, 2><<<dim3(M_PAD / 128, D_HID / 128), 256, 0, stream>>>(
        x, w1t, sup1, D_IN, N_NODES, N_NODES, D_HID);
    agg1_kernel<<<M_PAD / 4, 256, 0, stream>>>((const uint4*)sup1, offsets, edges, b1, hb);

    // ---- layer 2: sup2(bf16) = hb @ w2t^T ; out = log_softmax(agg + b2) ----
    gemm_bf16_kernel<64, 4, 1, 2, 4, false, 1><<<dim3(M_PAD / 128, 1), 256, 0, stream>>>(
        hb, w2t, sup2, D_HID, N_NODES, M_PAD, D_OUT);
    agg2_softmax_kernel<<<(N_NODES + 3) / 4, 256, 0, stream>>>((const uint2*)sup2,
                                                               offsets, edges, b2, out);
}